// Round 15
// baseline (481.388 us; speedup 1.0000x reference)
//
#include <hip/hip_runtime.h>
#include <hip/hip_fp16.h>
#include <cmath>
#include <cstring>

#define NN 50000
#define EE 800000
#define ET 850000        // EE + NN self-loops
#define PADCAP 1004544   // >= padded ET + slack; mult of 256
#define NBK 831          // edge blocks: 831*1024 >= ET
#define EBINS 196        // dst buckets of 256 nodes
#define DB 512           // degree-sort bins
#define NB 50            // degree-sort blocks

typedef unsigned int v4u __attribute__((ext_vector_type(4)));  // nontemporal-compatible

// ---------------- binned CSR build (no global atomics, dense writes) ----------------
__global__ __launch_bounds__(1024) void k_ebhist(const int* __restrict__ ei,
                                                 int* __restrict__ ebh){
  __shared__ int hist[EBINS];
  int t = threadIdx.x, b = blockIdx.x;
  if (t < EBINS) hist[t] = 0;
  __syncthreads();
  int e = b*1024 + t;
  if (e < ET){
    int d = (e < EE) ? ei[EE + e] : (e - EE);
    atomicAdd(&hist[d >> 8], 1);
  }
  __syncthreads();
  if (t < EBINS) ebh[t*NBK + b] = hist[t];
}

__global__ __launch_bounds__(1024) void k_escan1(const int* __restrict__ ebh,
                                                 int* __restrict__ ebhoff,
                                                 int* __restrict__ btot){
  __shared__ int tmp[1024];
  int bin = blockIdx.x, t = threadIdx.x;
  int v = (t < NBK) ? ebh[bin*NBK + t] : 0;
  int inc = v;
  for (int off = 1; off < 1024; off <<= 1){
    tmp[t] = inc; __syncthreads();
    int add = (t >= off) ? tmp[t - off] : 0;
    __syncthreads();
    inc += add;
  }
  if (t < NBK) ebhoff[bin*NBK + t] = inc - v;
  if (t == 1023) btot[bin] = inc;
}

__global__ __launch_bounds__(256) void k_escan2(const int* __restrict__ btot,
                                                int* __restrict__ bbase){
  __shared__ int tmp[256];
  int t = threadIdx.x;
  int v = (t < EBINS) ? btot[t] : 0;
  int inc = v;
  for (int off = 1; off < 256; off <<= 1){
    tmp[t] = inc; __syncthreads();
    int add = (t >= off) ? tmp[t - off] : 0;
    __syncthreads();
    inc += add;
  }
  if (t < EBINS) bbase[t] = inc - v;
  if (t == 255) bbase[EBINS] = inc;   // == ET
}

// packed entry: s (16 bits, NN<65536) | (d&255)<<16
__global__ __launch_bounds__(1024) void k_ebin(const int* __restrict__ ei,
                                               const int* __restrict__ ebhoff,
                                               const int* __restrict__ bbase,
                                               int* __restrict__ ebuf){
  __shared__ int hist[EBINS];
  int t = threadIdx.x, b = blockIdx.x;
  if (t < EBINS) hist[t] = 0;
  __syncthreads();
  int e = b*1024 + t;
  if (e < ET){
    int s, d;
    if (e < EE){ s = ei[e]; d = ei[EE + e]; } else { s = d = e - EE; }
    int bin = d >> 8;
    int rank = atomicAdd(&hist[bin], 1);
    int pos = bbase[bin] + ebhoff[bin*NBK + b] + rank;
    ebuf[pos] = s | ((d & 255) << 16);
  }
}

__global__ __launch_bounds__(1024) void k_ecnt(const int* __restrict__ ebuf,
                                               const int* __restrict__ bbase,
                                               int* __restrict__ count){
  __shared__ int cnt[256];
  int t = threadIdx.x, bin = blockIdx.x;
  if (t < 256) cnt[t] = 0;
  __syncthreads();
  int rb = bbase[bin], re = bbase[bin+1];
  for (int i = rb + t; i < re; i += 1024) atomicAdd(&cnt[(ebuf[i] >> 16) & 255], 1);
  __syncthreads();
  int idx = (bin << 8) + t;
  if (t < 256 && idx < NN) count[idx] = cnt[t];
}

// ---------------- offs scan (padded to x4 for int4 idx alignment) ----------------
__global__ void k_bsum(const int* __restrict__ count, int* __restrict__ bsums){
  int i = blockIdx.x*256 + threadIdx.x;
  int v = (i < NN) ? ((count[i] + 3) & ~3) : 0;
  #pragma unroll
  for (int m = 1; m < 64; m <<= 1) v += __shfl_xor(v, m);
  __shared__ int ws[4];
  if ((threadIdx.x & 63) == 0) ws[threadIdx.x >> 6] = v;
  __syncthreads();
  if (threadIdx.x == 0) bsums[blockIdx.x] = ws[0] + ws[1] + ws[2] + ws[3];
}

__global__ void k_bscan(const int* __restrict__ bsums, int* __restrict__ boffs, int nb){
  __shared__ int tmp[256];
  int t = threadIdx.x;
  int self = (t < nb) ? bsums[t] : 0;
  int v = self;
  for (int off = 1; off < 256; off <<= 1){
    tmp[t] = v; __syncthreads();
    int add = (t >= off) ? tmp[t - off] : 0;
    __syncthreads();
    v += add;
  }
  if (t < nb) boffs[t] = v - self;   // exclusive
}

// scan + write pad-slot sentinels (replaces the full-array k_fill)
__global__ void k_scan(const int* __restrict__ count, const int* __restrict__ boffs,
                       int* __restrict__ offs, int* __restrict__ srcCSR){
  __shared__ int tmp[256];
  int t = threadIdx.x;
  int gid = blockIdx.x*256 + t;
  int cnt = (gid < NN) ? count[gid] : 0;
  int self = (cnt + 3) & ~3;
  int v = self;
  for (int off = 1; off < 256; off <<= 1){
    tmp[t] = v; __syncthreads();
    int add = (t >= off) ? tmp[t - off] : 0;
    __syncthreads();
    v += add;
  }
  int excl = v - self + boffs[blockIdx.x];
  if (gid < NN){
    offs[gid] = excl;
    for (int k = cnt; k < self; ++k) srcCSR[excl + k] = NN;   // <=3 sentinels
  }
  if (gid == NN-1) offs[NN] = excl + self;   // padded total
}

__global__ __launch_bounds__(1024) void k_escatter(const int* __restrict__ ebuf,
                                                   const int* __restrict__ bbase,
                                                   const int* __restrict__ offs,
                                                   int* __restrict__ srcCSR){
  __shared__ int cur[256];
  int t = threadIdx.x, bin = blockIdx.x;
  if (t < 256){ int idx = (bin << 8) + t; cur[t] = (idx < NN) ? offs[idx] : 0; }
  __syncthreads();
  int rb = bbase[bin], re = bbase[bin+1];
  for (int i = rb + t; i < re; i += 1024){
    int v = ebuf[i];
    int p = atomicAdd(&cur[(v >> 16) & 255], 1);
    srcCSR[p] = v & 0xFFFF;
  }
}

// ---------------- degree sort (descending), block-local counting sort ----------------
__global__ __launch_bounds__(1024) void k_dhist_blk(const int* __restrict__ count,
                                                    int* __restrict__ blockhist){
  __shared__ int hist[DB];
  int t = threadIdx.x, b = blockIdx.x;
  if (t < DB) hist[t] = 0;
  __syncthreads();
  int i = b*1024 + t;
  if (i < NN){
    int deg = count[i]; if (deg > DB-1) deg = DB-1;
    atomicAdd(&hist[DB-1-deg], 1);
  }
  __syncthreads();
  if (t < DB) blockhist[t*NB + b] = hist[t];
}

__global__ __launch_bounds__(DB) void k_dcol(const int* __restrict__ blockhist,
                                             int* __restrict__ blockoffs,
                                             int* __restrict__ dbase){
  int k = threadIdx.x;
  int run = 0;
  #pragma unroll 5
  for (int b = 0; b < NB; ++b){
    int v = blockhist[k*NB + b];
    blockoffs[k*NB + b] = run;
    run += v;
  }
  __shared__ int tmp[DB];
  int v = run;
  for (int off = 1; off < DB; off <<= 1){
    tmp[k] = v; __syncthreads();
    int add = (k >= off) ? tmp[k - off] : 0;
    __syncthreads();
    v += add;
  }
  dbase[k] = v - run;
}

__global__ __launch_bounds__(1024) void k_dscatter_blk(const int* __restrict__ count,
                                                       const int* __restrict__ blockoffs,
                                                       const int* __restrict__ dbase,
                                                       int* __restrict__ perm){
  __shared__ int hist[DB];
  int t = threadIdx.x, b = blockIdx.x;
  if (t < DB) hist[t] = 0;
  __syncthreads();
  int i = b*1024 + t;
  if (i < NN){
    int deg = count[i]; if (deg > DB-1) deg = DB-1;
    int bin = DB-1-deg;
    int rank = atomicAdd(&hist[bin], 1);
    int pos = dbase[bin] + blockoffs[bin*NB + b] + rank;
    perm[pos] = i;
  }
}

// ---------------- fp16 helpers ----------------
__device__ __forceinline__ void cvt8v(v4u r, float* v){
  __half2 h;
  unsigned u0 = r.x, u1 = r.y, u2 = r.z, u3 = r.w;
  memcpy(&h, &u0, 4); float2 f = __half22float2(h); v[0]=f.x; v[1]=f.y;
  memcpy(&h, &u1, 4); f = __half22float2(h); v[2]=f.x; v[3]=f.y;
  memcpy(&h, &u2, 4); f = __half22float2(h); v[4]=f.x; v[5]=f.y;
  memcpy(&h, &u3, 4); f = __half22float2(h); v[6]=f.x; v[7]=f.y;
}
__device__ __forceinline__ unsigned pack_h2(float x, float y){
  __half2 h = __floats2half2_rn(x, y);
  unsigned u; memcpy(&u, &h, 4); return u;
}

// ---------------- compute ----------------
// 32 nodes/block. LDS-staged x tile (transposed, stride 33), w0/w1 in LDS,
// thread owns (node, 4 cols). hs aliases w0s (dead after phase 1).
__global__ __launch_bounds__(256) void k_prologue(
    const float* __restrict__ x, const float* __restrict__ W0, const float* __restrict__ b0,
    const float* __restrict__ Ws0, __half* __restrict__ hp_out){
  __shared__ __align__(16) float xs[128*33];   // xs[j*33+n]
  __shared__ __align__(16) float w0s[128*32];  // also hs[32*36] after phase 1
  __shared__ __align__(16) float w1s[32*32];
  int t = threadIdx.x, b = blockIdx.x;
  #pragma unroll
  for (int k = 0; k < 4; ++k){
    int i = t + k*256;               // 0..1023: n=i>>5, j4=(i&31)*4
    int n = i >> 5, j4 = (i & 31) << 2;
    int r = b*32 + n;
    const float4* src = (const float4*)(x + (size_t)((r < NN) ? r : 0)*128);
    float4 v = src[i & 31];
    xs[(j4+0)*33 + n] = v.x;
    xs[(j4+1)*33 + n] = v.y;
    xs[(j4+2)*33 + n] = v.z;
    xs[(j4+3)*33 + n] = v.w;
  }
  {
    const float4* w04 = (const float4*)W0;
    float4* dst = (float4*)w0s;
    #pragma unroll
    for (int k = 0; k < 4; ++k) dst[t + k*256] = w04[t + k*256];
    ((float4*)w1s)[t] = ((const float4*)Ws0)[t];
  }
  __syncthreads();
  int nloc = t >> 3, c8 = t & 7;        // cols 4*c8 .. 4*c8+3
  float4 acc = ((const float4*)b0)[c8];
  const float* xcol = xs + nloc;
  const float4* w0r = (const float4*)w0s + c8;
  #pragma unroll 8
  for (int j = 0; j < 128; ++j){
    float xv = xcol[j*33];
    float4 wv = w0r[j*8];
    acc.x += xv*wv.x; acc.y += xv*wv.y; acc.z += xv*wv.z; acc.w += xv*wv.w;
  }
  __syncthreads();                      // all reads of w0s done -> reuse as hs
  float* hs = w0s;                      // hs[32*36]
  ((float4*)(hs + nloc*36))[c8] = acc;  // same-octet write->read (same wave)
  float4 o = {0.f,0.f,0.f,0.f};
  const float* hrow = hs + nloc*36;
  const float4* w1r = (const float4*)w1s + c8;
  #pragma unroll 8
  for (int j = 0; j < 32; ++j){
    float hv = hrow[j];
    float4 wv = w1r[j*8];
    o.x += hv*wv.x; o.y += hv*wv.y; o.z += hv*wv.z; o.w += hv*wv.w;
  }
  int n = b*32 + nloc;
  if (n < NN){
    uint2 st; st.x = pack_h2(o.x, o.y); st.y = pack_h2(o.z, o.w);
    *(uint2*)(hp_out + (size_t)n*32 + (c8 << 2)) = st;
  }
  if (b == 0 && t < 32) hp_out[(size_t)NN*32 + t] = __float2half(0.f);  // pad row
}

// One SuperGAT layer — EXACT R11 structure (best measured: 436 us total).
// QUARTET (4 lanes) = one dst, 16 dst/wave. hl/hr on the fly. Double-buffered
// 2-group pipeline (rows depth 1, idx depth 2). Row gathers use nontemporal
// loads via ext_vector_type (no per-CU reuse -> skip L1 allocation).
__global__ __launch_bounds__(256) void k_layer(
    const __half* __restrict__ hp,
    const int* __restrict__ offs, const int* __restrict__ srcCSR, const int* __restrict__ perm,
    const float* __restrict__ bcur, const float* __restrict__ alc, const float* __restrict__ arc,
    const float* __restrict__ Wn, const float* __restrict__ b16,
    __half* __restrict__ hp_out, float* __restrict__ final_out, int last){
  __shared__ __align__(16) float wl[1024];
  __shared__ __align__(16) float xb[64*36];
  int t = threadIdx.x;
  int nW = last ? 512 : 1024;
  for (int i = t; i < nW; i += 256) wl[i] = Wn[i];   // barrier deferred to epilogue
  int lane = t & 63;
  int li = lane & 3;                // quartet lane: owns features 8li..8li+7
  int slot = t >> 2;                // 0..63 dst slot within block
  int gs = blockIdx.x*64 + slot;
  int d = (gs < NN) ? perm[gs] : NN;
  int beg = (d < NN) ? offs[d] : 0;     // multiple of 4 -> int4 aligned
  int ng  = (d < NN) ? ((offs[d+1] - beg) >> 2) : 0;
  float hpd[8];
  {
    v4u rd = *((const v4u*)(hp + ((size_t)d << 5)) + li);
    cvt8v(rd, hpd);
  }
  float4 ala = ((const float4*)alc)[2*li], alb = ((const float4*)alc)[2*li+1];
  float4 ara = ((const float4*)arc)[2*li], arb = ((const float4*)arc)[2*li+1];
  // hr_d = hp_d . att_r  (quartet reduce, once per dst)
  float hrd = hpd[0]*ara.x + hpd[1]*ara.y + hpd[2]*ara.z + hpd[3]*ara.w
            + hpd[4]*arb.x + hpd[5]*arb.y + hpd[6]*arb.z + hpd[7]*arb.w;
  hrd += __shfl_xor(hrd, 1); hrd += __shfl_xor(hrd, 2);

  int maxg = ng;
  #pragma unroll
  for (int m = 1; m < 64; m <<= 1) maxg = max(maxg, __shfl_xor(maxg, m));

  auto LD4 = [&](int g)->int4{
    int4 q = *(const int4*)(srcCSR + beg + (g << 2));   // in-bounds via slack
    if (g >= ng){ q.x = NN; q.y = NN; q.z = NN; q.w = NN; }  // overrun -> pad row
    return q;
  };
  auto ROW = [&](int s)->v4u{
    return __builtin_nontemporal_load((const v4u*)(hp + ((size_t)s << 5)) + li);
  };
  float acc[8] = {0.f,0.f,0.f,0.f,0.f,0.f,0.f,0.f};
  float den = 0.f;
  auto EDGE = [&](v4u r, int s){
    float v[8];
    cvt8v(r, v);
    float p = v[0]*hpd[0] + v[1]*hpd[1] + v[2]*hpd[2] + v[3]*hpd[3]
            + v[4]*hpd[4] + v[5]*hpd[5] + v[6]*hpd[6] + v[7]*hpd[7];
    float q = v[0]*ala.x + v[1]*ala.y + v[2]*ala.z + v[3]*ala.w
            + v[4]*alb.x + v[5]*alb.y + v[6]*alb.z + v[7]*alb.w;
    p += __shfl_xor(p, 1); p += __shfl_xor(p, 2);
    q += __shfl_xor(q, 1); q += __shfl_xor(q, 2);
    float a = (q + hrd) * (1.f/(1.f + __expf(-p)));
    a = fmaxf(a, 0.2f*a);
    float e = __expf(a);
    e = (s < NN) ? e : 0.f;           // pad/overrun edges contribute nothing
    den += e;
    #pragma unroll
    for (int k = 0; k < 8; ++k) acc[k] += v[k]*e;
  };

  // pipeline preamble: group0 rows, group1 idx
  int4 qA = LD4(0);
  v4u rA0=ROW(qA.x), rA1=ROW(qA.y), rA2=ROW(qA.z), rA3=ROW(qA.w);
  int4 qB = LD4(1);

  for (int g = 0; g < maxg; g += 2){
    v4u rB0=ROW(qB.x), rB1=ROW(qB.y), rB2=ROW(qB.z), rB3=ROW(qB.w);
    int4 qN = LD4(g + 2);
    EDGE(rA0,qA.x); EDGE(rA1,qA.y); EDGE(rA2,qA.z); EDGE(rA3,qA.w);
    rA0=ROW(qN.x); rA1=ROW(qN.y); rA2=ROW(qN.z); rA3=ROW(qN.w);
    qA = qN;
    int4 qB2 = LD4(g + 3);
    EDGE(rB0,qB.x); EDGE(rB1,qB.y); EDGE(rB2,qB.z); EDGE(rB3,qB.w);
    qB = qB2;
  }

  float rden = 1.f/den;                 // dummy quartet: NaN, stores guarded
  const float4* bc4 = (const float4*)bcur;
  float4 ba = bc4[2*li], bb = bc4[2*li+1];
  float* hrow = xb + slot*36;
  {
    float4 h0, h1;
    h0.x = fmaxf(acc[0]*rden + ba.x, 0.f);
    h0.y = fmaxf(acc[1]*rden + ba.y, 0.f);
    h0.z = fmaxf(acc[2]*rden + ba.z, 0.f);
    h0.w = fmaxf(acc[3]*rden + ba.w, 0.f);
    h1.x = fmaxf(acc[4]*rden + bb.x, 0.f);
    h1.y = fmaxf(acc[5]*rden + bb.y, 0.f);
    h1.z = fmaxf(acc[6]*rden + bb.z, 0.f);
    h1.w = fmaxf(acc[7]*rden + bb.w, 0.f);
    *((float4*)hrow + 2*li) = h0;
    *((float4*)hrow + 2*li + 1) = h1;
  }
  __syncthreads();   // weight staging visible (xb is same-wave)

  const float4* wl4 = (const float4*)wl;
  if (!last){
    float o[8] = {0.f,0.f,0.f,0.f,0.f,0.f,0.f,0.f};
    #pragma unroll
    for (int k = 0; k < 32; ++k){
      float hk = hrow[k];
      float4 wa = wl4[k*8 + 2*li];
      float4 wb = wl4[k*8 + 2*li + 1];
      o[0]+=hk*wa.x; o[1]+=hk*wa.y; o[2]+=hk*wa.z; o[3]+=hk*wa.w;
      o[4]+=hk*wb.x; o[5]+=hk*wb.y; o[6]+=hk*wb.z; o[7]+=hk*wb.w;
    }
    if (d < NN){
      uint4 st;
      st.x = pack_h2(o[0], o[1]); st.y = pack_h2(o[2], o[3]);
      st.z = pack_h2(o[4], o[5]); st.w = pack_h2(o[6], o[7]);
      *(uint4*)(hp_out + ((size_t)d << 5) + (li << 3)) = st;
    }
    if (blockIdx.x == 0){
      if (t < 32) hp_out[(size_t)NN*32 + t] = __float2half(0.f);
    }
  } else {
    float4 o = ((const float4*)b16)[li];
    #pragma unroll
    for (int k = 0; k < 32; ++k){
      float hk = hrow[k];
      float4 wv = wl4[k*4 + li];
      o.x += hk*wv.x; o.y += hk*wv.y; o.z += hk*wv.z; o.w += hk*wv.w;
    }
    if (d < NN) *((float4*)(final_out + (size_t)d*16) + li) = o;
  }
}

extern "C" void kernel_launch(void* const* d_in, const int* in_sizes, int n_in,
                              void* d_out, int out_size, void* d_ws, size_t ws_size,
                              hipStream_t stream){
  const float* x   = (const float*)d_in[0];
  const int*   ei  = (const int*)  d_in[1];
  const float* W0  = (const float*)d_in[2];
  const float* b0  = (const float*)d_in[3];
  const float* Ws  = (const float*)d_in[4];
  const float* al  = (const float*)d_in[5];
  const float* ar  = (const float*)d_in[6];
  const float* bs  = (const float*)d_in[7];
  const float* W16 = (const float*)d_in[8];
  const float* b16 = (const float*)d_in[9];
  float* out = (float*)d_out;

  char* w = (char*)d_ws;
  int* count     = (int*)w;   w += 50176*sizeof(int);
  int* offs      = (int*)w;   w += 50432*sizeof(int);
  int* srcCSR    = (int*)w;   w += (size_t)PADCAP*sizeof(int);
  int* bsums     = (int*)w;   w += 256*sizeof(int);
  int* boffs     = (int*)w;   w += 256*sizeof(int);
  int* perm      = (int*)w;   w += 50176*sizeof(int);
  int* blockhist = (int*)w;   w += DB*NB*sizeof(int);
  int* blockoffs = (int*)w;   w += DB*NB*sizeof(int);
  int* dbase     = (int*)w;   w += DB*sizeof(int);
  int* ebh       = (int*)w;   w += (size_t)EBINS*NBK*sizeof(int) + 16;
  int* ebhoff    = (int*)w;   w += (size_t)EBINS*NBK*sizeof(int) + 16;
  int* btot      = (int*)w;   w += 256*sizeof(int);
  int* bbase     = (int*)w;   w += 256*sizeof(int);
  int* ebuf      = (int*)w;   w += (size_t)(NBK*1024)*sizeof(int);
  __half* hpA  = (__half*)w; w += (size_t)(NN+16)*32*sizeof(__half);
  __half* hpB  = (__half*)w; w += (size_t)(NN+16)*32*sizeof(__half);
  // ~16 MB of d_ws

  // CSR build: bin -> scan -> scatter (no global atomics, dense writes)
  k_ebhist  <<<NBK, 1024, 0, stream>>>(ei, ebh);
  k_escan1  <<<EBINS, 1024, 0, stream>>>(ebh, ebhoff, btot);
  k_escan2  <<<1, 256, 0, stream>>>(btot, bbase);
  k_ebin    <<<NBK, 1024, 0, stream>>>(ei, ebhoff, bbase, ebuf);
  k_ecnt    <<<EBINS, 1024, 0, stream>>>(ebuf, bbase, count);
  k_bsum    <<<196, 256, 0, stream>>>(count, bsums);
  k_bscan   <<<1, 256, 0, stream>>>(bsums, boffs, 196);
  k_scan    <<<196, 256, 0, stream>>>(count, boffs, offs, srcCSR);
  k_escatter<<<EBINS, 1024, 0, stream>>>(ebuf, bbase, offs, srcCSR);
  // degree sort (descending)
  k_dhist_blk   <<<NB, 1024, 0, stream>>>(count, blockhist);
  k_dcol        <<<1,  DB,   0, stream>>>(blockhist, blockoffs, dbase);
  k_dscatter_blk<<<NB, 1024, 0, stream>>>(count, blockoffs, dbase, perm);

  // h0 = x@W0+b0 fused with layer-0 transform
  k_prologue<<<1563, 256, 0, stream>>>(x, W0, b0, Ws, hpA);

  int nblk = 50048 / 64;   // 782 blocks x 64 dst; slots >= NN guarded in-kernel
  for (int l = 0; l < 15; ++l){
    const __half* hin = (l & 1) ? hpB : hpA;
    __half* hout = (l & 1) ? hpA : hpB;
    int last = (l == 14);
    const float* Wn  = last ? W16 : (Ws + (size_t)(l+1)*1024);
    k_layer<<<nblk, 256, 0, stream>>>(hin, offs, srcCSR, perm,
                                      bs + (size_t)l*32,
                                      al + (size_t)l*32, ar + (size_t)l*32,
                                      Wn, b16,
                                      hout, out, last);
  }
}

// Round 16
// 428.392 us; speedup vs baseline: 1.1237x; 1.1237x over previous
//
#include <hip/hip_runtime.h>
#include <hip/hip_fp16.h>
#include <cmath>
#include <cstring>

#define NN 50000
#define EE 800000
#define ET 850000        // EE + NN self-loops
#define PADCAP 1004544   // >= padded ET + slack; mult of 256
#define NBK 831          // edge blocks: 831*1024 >= ET
#define EBINS 196        // dst buckets of 256 nodes
#define DB 512           // degree-sort bins
#define NB 50            // degree-sort blocks

// ---------------- binned CSR build (no global atomics, dense writes) ----------------
__global__ __launch_bounds__(1024) void k_ebhist(const int* __restrict__ ei,
                                                 int* __restrict__ ebh){
  __shared__ int hist[EBINS];
  int t = threadIdx.x, b = blockIdx.x;
  if (t < EBINS) hist[t] = 0;
  __syncthreads();
  int e = b*1024 + t;
  if (e < ET){
    int d = (e < EE) ? ei[EE + e] : (e - EE);
    atomicAdd(&hist[d >> 8], 1);
  }
  __syncthreads();
  if (t < EBINS) ebh[t*NBK + b] = hist[t];
}

__global__ __launch_bounds__(1024) void k_escan1(const int* __restrict__ ebh,
                                                 int* __restrict__ ebhoff,
                                                 int* __restrict__ btot){
  __shared__ int tmp[1024];
  int bin = blockIdx.x, t = threadIdx.x;
  int v = (t < NBK) ? ebh[bin*NBK + t] : 0;
  int inc = v;
  for (int off = 1; off < 1024; off <<= 1){
    tmp[t] = inc; __syncthreads();
    int add = (t >= off) ? tmp[t - off] : 0;
    __syncthreads();
    inc += add;
  }
  if (t < NBK) ebhoff[bin*NBK + t] = inc - v;
  if (t == 1023) btot[bin] = inc;
}

__global__ __launch_bounds__(256) void k_escan2(const int* __restrict__ btot,
                                                int* __restrict__ bbase){
  __shared__ int tmp[256];
  int t = threadIdx.x;
  int v = (t < EBINS) ? btot[t] : 0;
  int inc = v;
  for (int off = 1; off < 256; off <<= 1){
    tmp[t] = inc; __syncthreads();
    int add = (t >= off) ? tmp[t - off] : 0;
    __syncthreads();
    inc += add;
  }
  if (t < EBINS) bbase[t] = inc - v;
  if (t == 255) bbase[EBINS] = inc;   // == ET
}

// packed entry: s (16 bits, NN<65536) | (d&255)<<16
__global__ __launch_bounds__(1024) void k_ebin(const int* __restrict__ ei,
                                               const int* __restrict__ ebhoff,
                                               const int* __restrict__ bbase,
                                               int* __restrict__ ebuf){
  __shared__ int hist[EBINS];
  int t = threadIdx.x, b = blockIdx.x;
  if (t < EBINS) hist[t] = 0;
  __syncthreads();
  int e = b*1024 + t;
  if (e < ET){
    int s, d;
    if (e < EE){ s = ei[e]; d = ei[EE + e]; } else { s = d = e - EE; }
    int bin = d >> 8;
    int rank = atomicAdd(&hist[bin], 1);
    int pos = bbase[bin] + ebhoff[bin*NBK + b] + rank;
    ebuf[pos] = s | ((d & 255) << 16);
  }
}

__global__ __launch_bounds__(1024) void k_ecnt(const int* __restrict__ ebuf,
                                               const int* __restrict__ bbase,
                                               int* __restrict__ count){
  __shared__ int cnt[256];
  int t = threadIdx.x, bin = blockIdx.x;
  if (t < 256) cnt[t] = 0;
  __syncthreads();
  int rb = bbase[bin], re = bbase[bin+1];
  for (int i = rb + t; i < re; i += 1024) atomicAdd(&cnt[(ebuf[i] >> 16) & 255], 1);
  __syncthreads();
  int idx = (bin << 8) + t;
  if (t < 256 && idx < NN) count[idx] = cnt[t];
}

// ---------------- offs scan (padded to x4 for int4 idx alignment) ----------------
__global__ void k_bsum(const int* __restrict__ count, int* __restrict__ bsums){
  int i = blockIdx.x*256 + threadIdx.x;
  int v = (i < NN) ? ((count[i] + 3) & ~3) : 0;
  #pragma unroll
  for (int m = 1; m < 64; m <<= 1) v += __shfl_xor(v, m);
  __shared__ int ws[4];
  if ((threadIdx.x & 63) == 0) ws[threadIdx.x >> 6] = v;
  __syncthreads();
  if (threadIdx.x == 0) bsums[blockIdx.x] = ws[0] + ws[1] + ws[2] + ws[3];
}

__global__ void k_bscan(const int* __restrict__ bsums, int* __restrict__ boffs, int nb){
  __shared__ int tmp[256];
  int t = threadIdx.x;
  int self = (t < nb) ? bsums[t] : 0;
  int v = self;
  for (int off = 1; off < 256; off <<= 1){
    tmp[t] = v; __syncthreads();
    int add = (t >= off) ? tmp[t - off] : 0;
    __syncthreads();
    v += add;
  }
  if (t < nb) boffs[t] = v - self;   // exclusive
}

// scan + write pad-slot sentinels (replaces the full-array k_fill)
__global__ void k_scan(const int* __restrict__ count, const int* __restrict__ boffs,
                       int* __restrict__ offs, int* __restrict__ srcCSR){
  __shared__ int tmp[256];
  int t = threadIdx.x;
  int gid = blockIdx.x*256 + t;
  int cnt = (gid < NN) ? count[gid] : 0;
  int self = (cnt + 3) & ~3;
  int v = self;
  for (int off = 1; off < 256; off <<= 1){
    tmp[t] = v; __syncthreads();
    int add = (t >= off) ? tmp[t - off] : 0;
    __syncthreads();
    v += add;
  }
  int excl = v - self + boffs[blockIdx.x];
  if (gid < NN){
    offs[gid] = excl;
    for (int k = cnt; k < self; ++k) srcCSR[excl + k] = NN;   // <=3 sentinels
  }
  if (gid == NN-1) offs[NN] = excl + self;   // padded total
}

__global__ __launch_bounds__(1024) void k_escatter(const int* __restrict__ ebuf,
                                                   const int* __restrict__ bbase,
                                                   const int* __restrict__ offs,
                                                   int* __restrict__ srcCSR){
  __shared__ int cur[256];
  int t = threadIdx.x, bin = blockIdx.x;
  if (t < 256){ int idx = (bin << 8) + t; cur[t] = (idx < NN) ? offs[idx] : 0; }
  __syncthreads();
  int rb = bbase[bin], re = bbase[bin+1];
  for (int i = rb + t; i < re; i += 1024){
    int v = ebuf[i];
    int p = atomicAdd(&cur[(v >> 16) & 255], 1);
    srcCSR[p] = v & 0xFFFF;
  }
}

// ---------------- degree sort (descending), block-local counting sort ----------------
__global__ __launch_bounds__(1024) void k_dhist_blk(const int* __restrict__ count,
                                                    int* __restrict__ blockhist){
  __shared__ int hist[DB];
  int t = threadIdx.x, b = blockIdx.x;
  if (t < DB) hist[t] = 0;
  __syncthreads();
  int i = b*1024 + t;
  if (i < NN){
    int deg = count[i]; if (deg > DB-1) deg = DB-1;
    atomicAdd(&hist[DB-1-deg], 1);
  }
  __syncthreads();
  if (t < DB) blockhist[t*NB + b] = hist[t];
}

__global__ __launch_bounds__(DB) void k_dcol(const int* __restrict__ blockhist,
                                             int* __restrict__ blockoffs,
                                             int* __restrict__ dbase){
  int k = threadIdx.x;
  int run = 0;
  #pragma unroll 5
  for (int b = 0; b < NB; ++b){
    int v = blockhist[k*NB + b];
    blockoffs[k*NB + b] = run;
    run += v;
  }
  __shared__ int tmp[DB];
  int v = run;
  for (int off = 1; off < DB; off <<= 1){
    tmp[k] = v; __syncthreads();
    int add = (k >= off) ? tmp[k - off] : 0;
    __syncthreads();
    v += add;
  }
  dbase[k] = v - run;
}

__global__ __launch_bounds__(1024) void k_dscatter_blk(const int* __restrict__ count,
                                                       const int* __restrict__ blockoffs,
                                                       const int* __restrict__ dbase,
                                                       int* __restrict__ perm){
  __shared__ int hist[DB];
  int t = threadIdx.x, b = blockIdx.x;
  if (t < DB) hist[t] = 0;
  __syncthreads();
  int i = b*1024 + t;
  if (i < NN){
    int deg = count[i]; if (deg > DB-1) deg = DB-1;
    int bin = DB-1-deg;
    int rank = atomicAdd(&hist[bin], 1);
    int pos = dbase[bin] + blockoffs[bin*NB + b] + rank;
    perm[pos] = i;
  }
}

// ---------------- fp16 helpers ----------------
__device__ __forceinline__ void cvt8(uint4 r, float* v){
  __half2 h;
  memcpy(&h, &r.x, 4); float2 f = __half22float2(h); v[0]=f.x; v[1]=f.y;
  memcpy(&h, &r.y, 4); f = __half22float2(h); v[2]=f.x; v[3]=f.y;
  memcpy(&h, &r.z, 4); f = __half22float2(h); v[4]=f.x; v[5]=f.y;
  memcpy(&h, &r.w, 4); f = __half22float2(h); v[6]=f.x; v[7]=f.y;
}
__device__ __forceinline__ unsigned pack_h2(float x, float y){
  __half2 h = __floats2half2_rn(x, y);
  unsigned u; memcpy(&u, &h, 4); return u;
}

// ---------------- compute ----------------
// 32 nodes/block. LDS-staged x tile (transposed, stride 33), w0/w1 in LDS,
// thread owns (node, 4 cols). hs aliases w0s (dead after phase 1).
__global__ __launch_bounds__(256) void k_prologue(
    const float* __restrict__ x, const float* __restrict__ W0, const float* __restrict__ b0,
    const float* __restrict__ Ws0, __half* __restrict__ hp_out){
  __shared__ __align__(16) float xs[128*33];   // xs[j*33+n]
  __shared__ __align__(16) float w0s[128*32];  // also hs[32*36] after phase 1
  __shared__ __align__(16) float w1s[32*32];
  int t = threadIdx.x, b = blockIdx.x;
  #pragma unroll
  for (int k = 0; k < 4; ++k){
    int i = t + k*256;               // 0..1023: n=i>>5, j4=(i&31)*4
    int n = i >> 5, j4 = (i & 31) << 2;
    int r = b*32 + n;
    const float4* src = (const float4*)(x + (size_t)((r < NN) ? r : 0)*128);
    float4 v = src[i & 31];
    xs[(j4+0)*33 + n] = v.x;
    xs[(j4+1)*33 + n] = v.y;
    xs[(j4+2)*33 + n] = v.z;
    xs[(j4+3)*33 + n] = v.w;
  }
  {
    const float4* w04 = (const float4*)W0;
    float4* dst = (float4*)w0s;
    #pragma unroll
    for (int k = 0; k < 4; ++k) dst[t + k*256] = w04[t + k*256];
    ((float4*)w1s)[t] = ((const float4*)Ws0)[t];
  }
  __syncthreads();
  int nloc = t >> 3, c8 = t & 7;        // cols 4*c8 .. 4*c8+3
  float4 acc = ((const float4*)b0)[c8];
  const float* xcol = xs + nloc;
  const float4* w0r = (const float4*)w0s + c8;
  #pragma unroll 8
  for (int j = 0; j < 128; ++j){
    float xv = xcol[j*33];
    float4 wv = w0r[j*8];
    acc.x += xv*wv.x; acc.y += xv*wv.y; acc.z += xv*wv.z; acc.w += xv*wv.w;
  }
  __syncthreads();                      // all reads of w0s done -> reuse as hs
  float* hs = w0s;                      // hs[32*36]
  ((float4*)(hs + nloc*36))[c8] = acc;  // same-octet write->read (same wave)
  float4 o = {0.f,0.f,0.f,0.f};
  const float* hrow = hs + nloc*36;
  const float4* w1r = (const float4*)w1s + c8;
  #pragma unroll 8
  for (int j = 0; j < 32; ++j){
    float hv = hrow[j];
    float4 wv = w1r[j*8];
    o.x += hv*wv.x; o.y += hv*wv.y; o.z += hv*wv.z; o.w += hv*wv.w;
  }
  int n = b*32 + nloc;
  if (n < NN){
    uint2 st; st.x = pack_h2(o.x, o.y); st.y = pack_h2(o.z, o.w);
    *(uint2*)(hp_out + (size_t)n*32 + (c8 << 2)) = st;
  }
  if (b == 0 && t < 32) hp_out[(size_t)NN*32 + t] = __float2half(0.f);  // pad row
}

// One SuperGAT layer — EXACT R11 structure and gather path (plain uint4 row
// loads; the R15 nontemporal variant forfeited L1 hits on re-gathered popular
// src rows and regressed ~10%). QUARTET (4 lanes) = one dst, 16 dst/wave.
// hl/hr on the fly. Double-buffered 2-group pipeline (rows depth 1, idx depth 2).
__global__ __launch_bounds__(256) void k_layer(
    const __half* __restrict__ hp,
    const int* __restrict__ offs, const int* __restrict__ srcCSR, const int* __restrict__ perm,
    const float* __restrict__ bcur, const float* __restrict__ alc, const float* __restrict__ arc,
    const float* __restrict__ Wn, const float* __restrict__ b16,
    __half* __restrict__ hp_out, float* __restrict__ final_out, int last){
  __shared__ __align__(16) float wl[1024];
  __shared__ __align__(16) float xb[64*36];
  int t = threadIdx.x;
  int nW = last ? 512 : 1024;
  for (int i = t; i < nW; i += 256) wl[i] = Wn[i];   // barrier deferred to epilogue
  int lane = t & 63;
  int li = lane & 3;                // quartet lane: owns features 8li..8li+7
  int slot = t >> 2;                // 0..63 dst slot within block
  int gs = blockIdx.x*64 + slot;
  int d = (gs < NN) ? perm[gs] : NN;
  int beg = (d < NN) ? offs[d] : 0;     // multiple of 4 -> int4 aligned
  int ng  = (d < NN) ? ((offs[d+1] - beg) >> 2) : 0;
  float hpd[8];
  cvt8(*((const uint4*)(hp + ((size_t)d << 5)) + li), hpd);
  float4 ala = ((const float4*)alc)[2*li], alb = ((const float4*)alc)[2*li+1];
  float4 ara = ((const float4*)arc)[2*li], arb = ((const float4*)arc)[2*li+1];
  // hr_d = hp_d . att_r  (quartet reduce, once per dst)
  float hrd = hpd[0]*ara.x + hpd[1]*ara.y + hpd[2]*ara.z + hpd[3]*ara.w
            + hpd[4]*arb.x + hpd[5]*arb.y + hpd[6]*arb.z + hpd[7]*arb.w;
  hrd += __shfl_xor(hrd, 1); hrd += __shfl_xor(hrd, 2);

  int maxg = ng;
  #pragma unroll
  for (int m = 1; m < 64; m <<= 1) maxg = max(maxg, __shfl_xor(maxg, m));

  auto LD4 = [&](int g)->int4{
    int4 q = *(const int4*)(srcCSR + beg + (g << 2));   // in-bounds via slack
    if (g >= ng){ q.x = NN; q.y = NN; q.z = NN; q.w = NN; }  // overrun -> pad row
    return q;
  };
  auto ROW = [&](int s)->uint4{
    return *((const uint4*)(hp + ((size_t)s << 5)) + li);
  };
  float acc[8] = {0.f,0.f,0.f,0.f,0.f,0.f,0.f,0.f};
  float den = 0.f;
  auto EDGE = [&](uint4 r, int s){
    float v[8];
    cvt8(r, v);
    float p = v[0]*hpd[0] + v[1]*hpd[1] + v[2]*hpd[2] + v[3]*hpd[3]
            + v[4]*hpd[4] + v[5]*hpd[5] + v[6]*hpd[6] + v[7]*hpd[7];
    float q = v[0]*ala.x + v[1]*ala.y + v[2]*ala.z + v[3]*ala.w
            + v[4]*alb.x + v[5]*alb.y + v[6]*alb.z + v[7]*alb.w;
    p += __shfl_xor(p, 1); p += __shfl_xor(p, 2);
    q += __shfl_xor(q, 1); q += __shfl_xor(q, 2);
    float a = (q + hrd) * (1.f/(1.f + __expf(-p)));
    a = fmaxf(a, 0.2f*a);
    float e = __expf(a);
    e = (s < NN) ? e : 0.f;           // pad/overrun edges contribute nothing
    den += e;
    #pragma unroll
    for (int k = 0; k < 8; ++k) acc[k] += v[k]*e;
  };

  // pipeline preamble: group0 rows, group1 idx
  int4 qA = LD4(0);
  uint4 rA0=ROW(qA.x), rA1=ROW(qA.y), rA2=ROW(qA.z), rA3=ROW(qA.w);
  int4 qB = LD4(1);

  for (int g = 0; g < maxg; g += 2){
    uint4 rB0=ROW(qB.x), rB1=ROW(qB.y), rB2=ROW(qB.z), rB3=ROW(qB.w);
    int4 qN = LD4(g + 2);
    EDGE(rA0,qA.x); EDGE(rA1,qA.y); EDGE(rA2,qA.z); EDGE(rA3,qA.w);
    rA0=ROW(qN.x); rA1=ROW(qN.y); rA2=ROW(qN.z); rA3=ROW(qN.w);
    qA = qN;
    int4 qB2 = LD4(g + 3);
    EDGE(rB0,qB.x); EDGE(rB1,qB.y); EDGE(rB2,qB.z); EDGE(rB3,qB.w);
    qB = qB2;
  }

  float rden = 1.f/den;                 // dummy quartet: NaN, stores guarded
  const float4* bc4 = (const float4*)bcur;
  float4 ba = bc4[2*li], bb = bc4[2*li+1];
  float* hrow = xb + slot*36;
  {
    float4 h0, h1;
    h0.x = fmaxf(acc[0]*rden + ba.x, 0.f);
    h0.y = fmaxf(acc[1]*rden + ba.y, 0.f);
    h0.z = fmaxf(acc[2]*rden + ba.z, 0.f);
    h0.w = fmaxf(acc[3]*rden + ba.w, 0.f);
    h1.x = fmaxf(acc[4]*rden + bb.x, 0.f);
    h1.y = fmaxf(acc[5]*rden + bb.y, 0.f);
    h1.z = fmaxf(acc[6]*rden + bb.z, 0.f);
    h1.w = fmaxf(acc[7]*rden + bb.w, 0.f);
    *((float4*)hrow + 2*li) = h0;
    *((float4*)hrow + 2*li + 1) = h1;
  }
  __syncthreads();   // weight staging visible (xb is same-wave)

  const float4* wl4 = (const float4*)wl;
  if (!last){
    float o[8] = {0.f,0.f,0.f,0.f,0.f,0.f,0.f,0.f};
    #pragma unroll
    for (int k = 0; k < 32; ++k){
      float hk = hrow[k];
      float4 wa = wl4[k*8 + 2*li];
      float4 wb = wl4[k*8 + 2*li + 1];
      o[0]+=hk*wa.x; o[1]+=hk*wa.y; o[2]+=hk*wa.z; o[3]+=hk*wa.w;
      o[4]+=hk*wb.x; o[5]+=hk*wb.y; o[6]+=hk*wb.z; o[7]+=hk*wb.w;
    }
    if (d < NN){
      uint4 st;
      st.x = pack_h2(o[0], o[1]); st.y = pack_h2(o[2], o[3]);
      st.z = pack_h2(o[4], o[5]); st.w = pack_h2(o[6], o[7]);
      *(uint4*)(hp_out + ((size_t)d << 5) + (li << 3)) = st;
    }
    if (blockIdx.x == 0){
      if (t < 32) hp_out[(size_t)NN*32 + t] = __float2half(0.f);
    }
  } else {
    float4 o = ((const float4*)b16)[li];
    #pragma unroll
    for (int k = 0; k < 32; ++k){
      float hk = hrow[k];
      float4 wv = wl4[k*4 + li];
      o.x += hk*wv.x; o.y += hk*wv.y; o.z += hk*wv.z; o.w += hk*wv.w;
    }
    if (d < NN) *((float4*)(final_out + (size_t)d*16) + li) = o;
  }
}

extern "C" void kernel_launch(void* const* d_in, const int* in_sizes, int n_in,
                              void* d_out, int out_size, void* d_ws, size_t ws_size,
                              hipStream_t stream){
  const float* x   = (const float*)d_in[0];
  const int*   ei  = (const int*)  d_in[1];
  const float* W0  = (const float*)d_in[2];
  const float* b0  = (const float*)d_in[3];
  const float* Ws  = (const float*)d_in[4];
  const float* al  = (const float*)d_in[5];
  const float* ar  = (const float*)d_in[6];
  const float* bs  = (const float*)d_in[7];
  const float* W16 = (const float*)d_in[8];
  const float* b16 = (const float*)d_in[9];
  float* out = (float*)d_out;

  char* w = (char*)d_ws;
  int* count     = (int*)w;   w += 50176*sizeof(int);
  int* offs      = (int*)w;   w += 50432*sizeof(int);
  int* srcCSR    = (int*)w;   w += (size_t)PADCAP*sizeof(int);
  int* bsums     = (int*)w;   w += 256*sizeof(int);
  int* boffs     = (int*)w;   w += 256*sizeof(int);
  int* perm      = (int*)w;   w += 50176*sizeof(int);
  int* blockhist = (int*)w;   w += DB*NB*sizeof(int);
  int* blockoffs = (int*)w;   w += DB*NB*sizeof(int);
  int* dbase     = (int*)w;   w += DB*sizeof(int);
  int* ebh       = (int*)w;   w += (size_t)EBINS*NBK*sizeof(int) + 16;
  int* ebhoff    = (int*)w;   w += (size_t)EBINS*NBK*sizeof(int) + 16;
  int* btot      = (int*)w;   w += 256*sizeof(int);
  int* bbase     = (int*)w;   w += 256*sizeof(int);
  int* ebuf      = (int*)w;   w += (size_t)(NBK*1024)*sizeof(int);
  __half* hpA  = (__half*)w; w += (size_t)(NN+16)*32*sizeof(__half);
  __half* hpB  = (__half*)w; w += (size_t)(NN+16)*32*sizeof(__half);
  // ~16 MB of d_ws

  // CSR build: bin -> scan -> scatter (no global atomics, dense writes)
  k_ebhist  <<<NBK, 1024, 0, stream>>>(ei, ebh);
  k_escan1  <<<EBINS, 1024, 0, stream>>>(ebh, ebhoff, btot);
  k_escan2  <<<1, 256, 0, stream>>>(btot, bbase);
  k_ebin    <<<NBK, 1024, 0, stream>>>(ei, ebhoff, bbase, ebuf);
  k_ecnt    <<<EBINS, 1024, 0, stream>>>(ebuf, bbase, count);
  k_bsum    <<<196, 256, 0, stream>>>(count, bsums);
  k_bscan   <<<1, 256, 0, stream>>>(bsums, boffs, 196);
  k_scan    <<<196, 256, 0, stream>>>(count, boffs, offs, srcCSR);
  k_escatter<<<EBINS, 1024, 0, stream>>>(ebuf, bbase, offs, srcCSR);
  // degree sort (descending)
  k_dhist_blk   <<<NB, 1024, 0, stream>>>(count, blockhist);
  k_dcol        <<<1,  DB,   0, stream>>>(blockhist, blockoffs, dbase);
  k_dscatter_blk<<<NB, 1024, 0, stream>>>(count, blockoffs, dbase, perm);

  // h0 = x@W0+b0 fused with layer-0 transform
  k_prologue<<<1563, 256, 0, stream>>>(x, W0, b0, Ws, hpA);

  int nblk = 50048 / 64;   // 782 blocks x 64 dst; slots >= NN guarded in-kernel
  for (int l = 0; l < 15; ++l){
    const __half* hin = (l & 1) ? hpB : hpA;
    __half* hout = (l & 1) ? hpA : hpB;
    int last = (l == 14);
    const float* Wn  = last ? W16 : (Ws + (size_t)(l+1)*1024);
    k_layer<<<nblk, 256, 0, stream>>>(hin, offs, srcCSR, perm,
                                      bs + (size_t)l*32,
                                      al + (size_t)l*32, ar + (size_t)l*32,
                                      Wn, b16,
                                      hout, out, last);
  }
}